// Round 9
// baseline (639.997 us; speedup 1.0000x reference)
//
#include <hip/hip_runtime.h>
#include <hip/hip_bf16.h>
#include <hip/hip_cooperative_groups.h>

namespace cg = cooperative_groups;

// Graph Actor Model — R8: cooperative single-kernel pipeline with
// occupancy-sized grid and a full R6-proven multi-kernel fallback if the
// cooperative launch is rejected. One set of device functions serves both.

#define NN   8192
#define EPAD 128

typedef __attribute__((ext_vector_type(8))) short bf16x8;
typedef __attribute__((ext_vector_type(4))) float f32x4;

// weight image byte offsets (R6-proven layout, tile = BN*128 bytes)
#define IMG_E1  0u
#define IMG_E2  16384u
#define IMG_GCN 81920u
#define IMG_GD  344064u
#define IMG_P1  606208u
#define IMG_P2  868352u
#define IMG_PI  933888u

// ---------- split-bf16 helpers (R4/R6 proven) ----------

__device__ __forceinline__ unsigned f32_to_split(float v) {
    unsigned b = __builtin_bit_cast(unsigned, v);
    unsigned hi = (b + 0x7fffu + ((b >> 16) & 1u)) & 0xffff0000u;
    float lo = v - __builtin_bit_cast(float, hi);
    unsigned lb = __builtin_bit_cast(unsigned, lo);
    unsigned lo16 = (lb + 0x7fffu + ((lb >> 16) & 1u)) >> 16;
    return hi | lo16;
}

__device__ __forceinline__ void unpack_frags(const uint4& q0, const uint4& q1,
                                             bf16x8& hi, bf16x8& lo) {
    union { unsigned u[4]; bf16x8 v; } H, L;
    H.u[0] = (q0.y & 0xffff0000u) | (q0.x >> 16);
    H.u[1] = (q0.w & 0xffff0000u) | (q0.z >> 16);
    H.u[2] = (q1.y & 0xffff0000u) | (q1.x >> 16);
    H.u[3] = (q1.w & 0xffff0000u) | (q1.z >> 16);
    L.u[0] = (q0.y << 16) | (q0.x & 0xffffu);
    L.u[1] = (q0.w << 16) | (q0.z & 0xffffu);
    L.u[2] = (q1.y << 16) | (q1.x & 0xffffu);
    L.u[3] = (q1.w << 16) | (q1.z & 0xffffu);
    hi = H.v; lo = L.v;
}

__device__ __forceinline__ void split2(float v, unsigned short& h, unsigned short& l) {
    unsigned b = __builtin_bit_cast(unsigned, v);
    unsigned hr = (b + 0x7fffu + ((b >> 16) & 1u)) & 0xffff0000u;
    h = (unsigned short)(hr >> 16);
    float lo = v - __builtin_bit_cast(float, hr);
    unsigned lb = __builtin_bit_cast(unsigned, lo);
    l = (unsigned short)((lb + 0x7fffu + ((lb >> 16) & 1u)) >> 16);
}

__device__ __forceinline__ void splitfrag(const float4& v0, const float4& v1,
                                          bf16x8& ah, bf16x8& al) {
    union { unsigned short us[8]; bf16x8 v; } H, L;
    float vv[8] = {v0.x, v0.y, v0.z, v0.w, v1.x, v1.y, v1.z, v1.w};
    #pragma unroll
    for (int j = 0; j < 8; ++j) {
        unsigned short h, l;
        split2(vv[j], h, l);
        H.us[j] = h; L.us[j] = l;
    }
    ah = H.v; al = L.v;
}

__device__ __forceinline__ void gload_lds16(const void* g, void* l) {
    typedef const __attribute__((address_space(1))) unsigned int GU;
    typedef __attribute__((address_space(3))) unsigned int LU;
    __builtin_amdgcn_global_load_lds((GU*)g, (LU*)l, 16, 0, 0);
}

// ---------- build (8-deep independent loads, grid-size generic) ----------

__device__ __forceinline__ void handle_chunk(const uint4& v, size_t chunk,
                                             int* cnt, int* edges) {
    if ((v.x | v.y | v.z | v.w) != 0u) {
        size_t base = chunk * 4;
        int r  = (int)(base / NN);
        int c0 = (int)(base % NN);
        unsigned e[4] = {v.x, v.y, v.z, v.w};
        #pragma unroll
        for (int j = 0; j < 4; ++j) {
            if (e[j] != 0u) {
                int c = c0 + j;
                int slot = atomicAdd(&cnt[c], 1);
                if (slot < EPAD) edges[(size_t)c * EPAD + slot] = r;
            }
        }
    }
}

__device__ void build_part(const uint4* __restrict__ adj4,
                           int* __restrict__ cnt, int* __restrict__ edges,
                           size_t tid, size_t nthr) {
    const size_t total = (size_t)NN * NN / 4;
    const size_t nfull = total / (nthr * 8);
    for (size_t b = 0; b < nfull; ++b) {
        size_t i0 = tid + b * 8 * nthr;
        uint4 v0 = adj4[i0 + 0 * nthr];
        uint4 v1 = adj4[i0 + 1 * nthr];
        uint4 v2 = adj4[i0 + 2 * nthr];
        uint4 v3 = adj4[i0 + 3 * nthr];
        uint4 v4 = adj4[i0 + 4 * nthr];
        uint4 v5 = adj4[i0 + 5 * nthr];
        uint4 v6 = adj4[i0 + 6 * nthr];
        uint4 v7 = adj4[i0 + 7 * nthr];
        handle_chunk(v0, i0 + 0 * nthr, cnt, edges);
        handle_chunk(v1, i0 + 1 * nthr, cnt, edges);
        handle_chunk(v2, i0 + 2 * nthr, cnt, edges);
        handle_chunk(v3, i0 + 3 * nthr, cnt, edges);
        handle_chunk(v4, i0 + 4 * nthr, cnt, edges);
        handle_chunk(v5, i0 + 5 * nthr, cnt, edges);
        handle_chunk(v6, i0 + 6 * nthr, cnt, edges);
        handle_chunk(v7, i0 + 7 * nthr, cnt, edges);
    }
    for (size_t i = tid + nfull * 8 * nthr; i < total; i += nthr) {
        uint4 v = adj4[i];
        handle_chunk(v, i, cnt, edges);
    }
}

// ---------- weight image packing (R6-proven) ----------

__device__ void pack_layer(const float* W, int NOUT, int K, int BN_,
                           unsigned imgoff, int rank, int nblk,
                           unsigned char* img) {
    const int nks = K / 32;
    const int total = (NOUT / BN_) * nks * BN_ * 8;
    const int tileb = BN_ * 128;
    for (int u = rank * 256 + threadIdx.x; u < total; u += nblk * 256) {
        int tile = u / (BN_ * 8);
        int rem  = u - tile * (BN_ * 8);
        int n    = rem >> 3;
        int c    = rem & 7;
        int nh   = tile / nks;
        int ks   = tile - nh * nks;
        int col  = nh * BN_ + n;
        int kb   = ks * 32 + c * 4;
        uint4 q;
        q.x = f32_to_split(W[(size_t)(kb + 0) * NOUT + col]);
        q.y = f32_to_split(W[(size_t)(kb + 1) * NOUT + col]);
        q.z = f32_to_split(W[(size_t)(kb + 2) * NOUT + col]);
        q.w = f32_to_split(W[(size_t)(kb + 3) * NOUT + col]);
        *(uint4*)(img + imgoff + (size_t)tile * tileb + n * 128 + ((c ^ (n & 7)) << 4)) = q;
    }
}

__device__ void pack_dispatch(int pb,
    const float* We1, const float* We2, const float* Wgcn, const float* Wgd,
    const float* Wp1, const float* Wp2, const float* Wpi, unsigned char* img)
{
    if (pb < 2)      pack_layer(Wgcn, 256, 256, 64, IMG_GCN, pb,     2, img);
    else if (pb < 4) pack_layer(Wgd,  256, 256, 64, IMG_GD,  pb - 2, 2, img);
    else if (pb < 6) pack_layer(Wp1,  128, 512, 64, IMG_P1,  pb - 4, 2, img);
    else if (pb < 7) { pack_layer(We2, 256,  64, 64, IMG_E2, 0, 1, img);
                       pack_layer(Wp2, 128, 128, 64, IMG_P2, 0, 1, img); }
    else             { pack_layer(We1,  64,  64, 64, IMG_E1, 0, 1, img);
                       pack_layer(Wpi,  32, 128, 32, IMG_PI, 0, 1, img); }
}

// ---------- sparse propagation (R6-proven body) ----------

__device__ void prop_pair(const float* __restrict__ h, const int* __restrict__ cnt,
                          const int* __restrict__ edges, float* __restrict__ outp,
                          int pv, unsigned char* lds) {
    int*   se = (int*)lds;              // [2][128]
    float* sd = (float*)(lds + 1024);   // [2][128]
    const int half = threadIdx.x >> 7;
    const int tl   = threadIdx.x & 127;
    const int c = pv * 2 + half;
    int n = cnt[c]; if (n > EPAD) n = EPAD;
    if (tl < n) {
        int r = edges[(size_t)c * EPAD + tl];
        se[half * 128 + tl] = r;
        int dr = cnt[r];
        sd[half * 128 + tl] = dr > 0 ? rsqrtf((float)dr) : 0.f;
    }
    __syncthreads();
    float2 a[8];
    #pragma unroll
    for (int j = 0; j < 8; ++j) { a[j].x = 0.f; a[j].y = 0.f; }
    int i = 0;
    for (; i + 8 <= n; i += 8) {
        #pragma unroll
        for (int j = 0; j < 8; ++j) {
            float2 v = *(const float2*)&h[(size_t)se[half * 128 + i + j] * 256 + tl * 2];
            float s = sd[half * 128 + i + j];
            a[j].x += s * v.x; a[j].y += s * v.y;
        }
    }
    for (; i < n; ++i) {
        float2 v = *(const float2*)&h[(size_t)se[half * 128 + i] * 256 + tl * 2];
        float s = sd[half * 128 + i];
        a[0].x += s * v.x; a[0].y += s * v.y;
    }
    int dc = cnt[c];
    float di = dc > 0 ? rsqrtf((float)dc) : 0.f;
    float2 r2;
    r2.x = di * (((a[0].x + a[1].x) + (a[2].x + a[3].x)) + ((a[4].x + a[5].x) + (a[6].x + a[7].x)));
    r2.y = di * (((a[0].y + a[1].y) + (a[2].y + a[3].y)) + ((a[4].y + a[5].y) + (a[6].y + a[7].y)));
    *(float2*)&outp[(size_t)c * 256 + tl * 2] = r2;
}

// ---------- GEMM body (R6-proven gemm3 internals, position-parameterized) ----------

template<int K1, int K2, int NOUT, int BN, bool RELU, bool MASK>
__device__ void gemm_body(int row0, int col0,
    const float* __restrict__ A1, const float* __restrict__ A2,
    const unsigned char* __restrict__ imgp, const float* __restrict__ bias,
    float* __restrict__ C, const float* __restrict__ maskv,
    unsigned char* Bs)
{
    constexpr int K      = K1 + K2;
    constexpr int NKS    = K / 32;
    constexpr int TILEB  = BN * 128;
    constexpr int WTILES = NKS > 4 ? 4 : NKS;   // <=32 KB window
    constexpr int NWIN   = NKS / WTILES;
    constexpr int WN     = BN / 2;
    constexpr int FN     = WN / 16;
    constexpr int NCHUNK = WTILES * TILEB / 1024;

    const int t    = threadIdx.x;
    const int lane = t & 63;
    const int wave = t >> 6;
    const int wr   = wave >> 1;
    const int wc   = wave & 1;
    const int lm   = lane & 15;
    const int lk   = lane >> 4;

    f32x4 acc[2][FN];
    #pragma unroll
    for (int i = 0; i < 2; ++i)
        #pragma unroll
        for (int j = 0; j < FN; ++j) {
            acc[i][j][0] = 0.f; acc[i][j][1] = 0.f;
            acc[i][j][2] = 0.f; acc[i][j][3] = 0.f;
        }

    #pragma unroll
    for (int w = 0; w < NWIN; ++w) {
        if (w > 0) __syncthreads();
        #pragma unroll
        for (int i = wave; i < NCHUNK; i += 4)
            gload_lds16(imgp + (size_t)w * WTILES * TILEB + (size_t)i * 1024 + lane * 16,
                        Bs + (size_t)i * 1024);
        __syncthreads();

        #pragma unroll
        for (int kl = 0; kl < WTILES; ++kl) {
            const int ks = w * WTILES + kl;
            const int kg = ks * 32 + lk * 8;
            bf16x8 bh[FN], bl[FN];
            #pragma unroll
            for (int fn = 0; fn < FN; ++fn) {
                int n = wc * WN + fn * 16 + lm;
                const unsigned char* bb = Bs + kl * TILEB + n * 128;
                uint4 q0 = *(const uint4*)(bb + (((lk * 2 + 0) ^ (n & 7)) << 4));
                uint4 q1 = *(const uint4*)(bb + (((lk * 2 + 1) ^ (n & 7)) << 4));
                unpack_frags(q0, q1, bh[fn], bl[fn]);
            }
            #pragma unroll
            for (int fm = 0; fm < 2; ++fm) {
                int m = row0 + wr * 32 + fm * 16 + lm;
                const float* ap; int kk = kg;
                if constexpr (K2 > 0) {
                    if (kg < K1) { ap = A1 + (size_t)m * K1; }
                    else         { ap = A2 + (size_t)m * K2; kk = kg - K1; }
                } else {
                    ap = A1 + (size_t)m * K1;
                }
                float4 v0 = *(const float4*)(ap + kk);
                float4 v1 = *(const float4*)(ap + kk + 4);
                bf16x8 ah, al;
                splitfrag(v0, v1, ah, al);
                #pragma unroll
                for (int fn = 0; fn < FN; ++fn) {
                    acc[fm][fn] = __builtin_amdgcn_mfma_f32_16x16x32_bf16(ah, bh[fn], acc[fm][fn], 0, 0, 0);
                    acc[fm][fn] = __builtin_amdgcn_mfma_f32_16x16x32_bf16(ah, bl[fn], acc[fm][fn], 0, 0, 0);
                    acc[fm][fn] = __builtin_amdgcn_mfma_f32_16x16x32_bf16(al, bh[fn], acc[fm][fn], 0, 0, 0);
                }
            }
        }
    }

    #pragma unroll
    for (int fm = 0; fm < 2; ++fm) {
        #pragma unroll
        for (int fn = 0; fn < FN; ++fn) {
            int col = col0 + wc * WN + fn * 16 + lm;
            float b = bias[col];
            #pragma unroll
            for (int q = 0; q < 4; ++q) {
                int row = row0 + wr * 32 + fm * 16 + lk * 4 + q;
                float v = acc[fm][fn][q] + b;
                if (RELU) v = fmaxf(v, 0.f);
                if (MASK) v *= maskv[row];
                C[(size_t)row * NOUT + col] = v;
            }
        }
    }
}

// ---------- cooperative mega kernel (grid-size agnostic, >=8 blocks) ----------

__global__ __launch_bounds__(256, 2) void coop_kernel(
    const uint4* adj4, int* cnt, int* edges, const float* feat,
    const float* We1, const float* We2, const float* Wgcn, const float* Wgd,
    const float* Wp1, const float* Wp2, const float* Wpi,
    const float* be1, const float* be2, const float* bgcn, const float* bgd,
    const float* bp1, const float* bp2, const float* bpi,
    const float* maskv, float* X, float* T, float* Hs,
    unsigned char* img, float* out)
{
    __shared__ unsigned char Bs[32768];
    cg::grid_group grid = cg::this_grid();
    const int bid = blockIdx.x;
    const int nb  = gridDim.x;

    // A: pack (blocks 0..7) + build (all blocks)
    if (bid < 8) pack_dispatch(bid, We1, We2, Wgcn, Wgd, Wp1, Wp2, Wpi, img);
    build_part(adj4, cnt, edges, (size_t)bid * 256 + threadIdx.x, (size_t)nb * 256);
    grid.sync();

    // B: e1  T = relu(F @ We1 + b)   [NN,64]
    for (int vb = bid; vb < 128; vb += nb) {
        gemm_body<64, 0, 64, 64, true, false>(vb * 64, 0, feat, nullptr,
            img + IMG_E1, be1, T, nullptr, Bs);
        __syncthreads();
    }
    grid.sync();

    // C: e2  X = relu(T @ We2 + b)   [NN,256]
    for (int vb = bid; vb < 512; vb += nb) {
        gemm_body<64, 0, 256, 64, true, false>((vb >> 2) * 64, (vb & 3) * 64, T, nullptr,
            img + IMG_E2 + (size_t)(vb & 3) * 16384, be2, X, nullptr, Bs);
        __syncthreads();
    }
    grid.sync();

    // D: prop1  X -> T
    for (int pv = bid; pv < NN / 2; pv += nb) { prop_pair(X, cnt, edges, T, pv, Bs); __syncthreads(); }
    grid.sync();

    // E: prop2  T -> Hs
    for (int pv = bid; pv < NN / 2; pv += nb) { prop_pair(T, cnt, edges, Hs, pv, Bs); __syncthreads(); }
    grid.sync();

    // F: gcn  T = relu(Hs @ Wgcn + b)
    for (int vb = bid; vb < 512; vb += nb) {
        gemm_body<256, 0, 256, 64, true, false>((vb >> 2) * 64, (vb & 3) * 64, Hs, nullptr,
            img + IMG_GCN + (size_t)(vb & 3) * 65536, bgcn, T, nullptr, Bs);
        __syncthreads();
    }
    grid.sync();

    // G: gd  Hs = relu(T @ Wgd + b)
    for (int vb = bid; vb < 512; vb += nb) {
        gemm_body<256, 0, 256, 64, true, false>((vb >> 2) * 64, (vb & 3) * 64, T, nullptr,
            img + IMG_GD + (size_t)(vb & 3) * 65536, bgd, Hs, nullptr, Bs);
        __syncthreads();
    }
    grid.sync();

    // H: p1  T[:, :128] = relu([Hs | X] @ Wp1 + b)
    for (int vb = bid; vb < 256; vb += nb) {
        gemm_body<256, 256, 128, 64, true, false>((vb >> 1) * 64, (vb & 1) * 64, Hs, X,
            img + IMG_P1 + (size_t)(vb & 1) * 131072, bp1, T, nullptr, Bs);
        __syncthreads();
    }
    grid.sync();

    // I: p2  Hs[:, :128] = relu(T @ Wp2 + b)
    for (int vb = bid; vb < 256; vb += nb) {
        gemm_body<128, 0, 128, 64, true, false>((vb >> 1) * 64, (vb & 1) * 64, T, nullptr,
            img + IMG_P2 + (size_t)(vb & 1) * 32768, bp2, Hs, nullptr, Bs);
        __syncthreads();
    }
    grid.sync();

    // J: pi  out = (Hs @ Wpi + b) * mask
    for (int vb = bid; vb < 128; vb += nb) {
        gemm_body<128, 0, 32, 32, false, true>(vb * 64, 0, Hs, nullptr,
            img + IMG_PI, bpi, out, maskv, Bs);
        __syncthreads();
    }
}

// ---------- fallback kernels (R6 structure) ----------

__global__ __launch_bounds__(256) void buildpack_kernel(
    const uint4* adj4, int* cnt, int* edges,
    const float* We1, const float* We2, const float* Wgcn, const float* Wgd,
    const float* Wp1, const float* Wp2, const float* Wpi, unsigned char* img)
{
    int bid = blockIdx.x;
    if (bid < 2048)
        build_part(adj4, cnt, edges, (size_t)bid * 256 + threadIdx.x, (size_t)2048 * 256);
    else
        pack_dispatch(bid - 2048, We1, We2, Wgcn, Wgd, Wp1, Wp2, Wpi, img);
}

__global__ __launch_bounds__(256) void prop_kernel(
    const float* __restrict__ h, const int* __restrict__ cnt,
    const int* __restrict__ edges, float* __restrict__ out)
{
    __shared__ unsigned char lds[2048];
    prop_pair(h, cnt, edges, out, blockIdx.x, lds);
}

template<int K1, int K2, int NOUT, int BN, bool RELU, bool MASK>
__global__ __launch_bounds__(256) void gemm3(
    const float* __restrict__ A1, const float* __restrict__ A2,
    const unsigned char* __restrict__ img, const float* __restrict__ bias,
    float* __restrict__ C, const float* __restrict__ maskv)
{
    constexpr int NKS   = (K1 + K2) / 32;
    constexpr int TILEB = BN * 128;
    constexpr int WT    = NKS > 4 ? 4 : NKS;
    __shared__ unsigned char Bs[WT * TILEB];
    gemm_body<K1, K2, NOUT, BN, RELU, MASK>(
        blockIdx.x * 64, blockIdx.y * BN, A1, A2,
        img + (size_t)blockIdx.y * NKS * TILEB, bias, C, maskv, Bs);
}

// ---------- launch ----------

extern "C" void kernel_launch(void* const* d_in, const int* in_sizes, int n_in,
                              void* d_out, int out_size, void* d_ws, size_t ws_size,
                              hipStream_t stream) {
    const float* features = (const float*)d_in[0];
    const uint4* adj4     = (const uint4*)d_in[1];
    const float* mask     = (const float*)d_in[2];
    const float* W_e1  = (const float*)d_in[3];
    const float* b_e1  = (const float*)d_in[4];
    const float* W_e2  = (const float*)d_in[5];
    const float* b_e2  = (const float*)d_in[6];
    const float* W_gcn = (const float*)d_in[7];
    const float* b_gcn = (const float*)d_in[8];
    const float* W_gd  = (const float*)d_in[9];
    const float* b_gd  = (const float*)d_in[10];
    const float* W_p1  = (const float*)d_in[11];
    const float* b_p1  = (const float*)d_in[12];
    const float* W_p2  = (const float*)d_in[13];
    const float* b_p2  = (const float*)d_in[14];
    const float* W_pi  = (const float*)d_in[15];
    const float* b_pi  = (const float*)d_in[16];
    float* out = (float*)d_out;

    float* ws = (float*)d_ws;
    float* X   = ws;                                  // [NN,256]
    float* T   = X  + (size_t)NN * 256;               // [NN,256] (e1 out [NN,64], P1 [NN,128])
    float* Hs  = T  + (size_t)NN * 256;               // [NN,256] (P2 [NN,128])
    int* cnt   = (int*)(Hs + (size_t)NN * 256);       // [NN]
    int* edges = cnt + NN;                            // [NN][EPAD]
    unsigned char* img = (unsigned char*)(edges + (size_t)NN * EPAD);

    hipMemsetAsync(cnt, 0, NN * sizeof(int), stream);

    // --- try cooperative single-kernel path, sized by measured occupancy ---
    int occ = 0;
    hipError_t qe = hipOccupancyMaxActiveBlocksPerMultiprocessor(&occ, coop_kernel, 256, 0);
    int grid = 512;
    if (qe == hipSuccess && occ >= 1) {
        int g = occ * 256;                 // 256 CUs
        if (g < grid) grid = g;
    }

    bool coop_ok = false;
    if (grid >= 8) {
        void* args[] = {
            (void*)&adj4, (void*)&cnt, (void*)&edges, (void*)&features,
            (void*)&W_e1, (void*)&W_e2, (void*)&W_gcn, (void*)&W_gd,
            (void*)&W_p1, (void*)&W_p2, (void*)&W_pi,
            (void*)&b_e1, (void*)&b_e2, (void*)&b_gcn, (void*)&b_gd,
            (void*)&b_p1, (void*)&b_p2, (void*)&b_pi,
            (void*)&mask, (void*)&X, (void*)&T, (void*)&Hs,
            (void*)&img, (void*)&out
        };
        hipError_t le = hipLaunchCooperativeKernel((void*)coop_kernel, dim3(grid),
                                                   dim3(256), args, 0, stream);
        coop_ok = (le == hipSuccess);
        if (!coop_ok) (void)hipGetLastError();   // clear sticky error
    }

    if (!coop_ok) {
        // --- R6-proven fallback: 10 dispatches ---
        buildpack_kernel<<<2056, 256, 0, stream>>>(
            adj4, cnt, edges, W_e1, W_e2, W_gcn, W_gd, W_p1, W_p2, W_pi, img);

        gemm3<64, 0, 64, 64, true, false>
            <<<dim3(128, 1), 256, 0, stream>>>(features, nullptr, img + IMG_E1, b_e1, T, nullptr);
        gemm3<64, 0, 256, 64, true, false>
            <<<dim3(128, 4), 256, 0, stream>>>(T, nullptr, img + IMG_E2, b_e2, X, nullptr);

        prop_kernel<<<NN / 2, 256, 0, stream>>>(X, cnt, edges, T);
        prop_kernel<<<NN / 2, 256, 0, stream>>>(T, cnt, edges, Hs);

        gemm3<256, 0, 256, 64, true, false>
            <<<dim3(128, 4), 256, 0, stream>>>(Hs, nullptr, img + IMG_GCN, b_gcn, T, nullptr);
        gemm3<256, 0, 256, 64, true, false>
            <<<dim3(128, 4), 256, 0, stream>>>(T, nullptr, img + IMG_GD, b_gd, Hs, nullptr);

        gemm3<256, 256, 128, 64, true, false>
            <<<dim3(128, 2), 256, 0, stream>>>(Hs, X, img + IMG_P1, b_p1, T, nullptr);
        gemm3<128, 0, 128, 64, true, false>
            <<<dim3(128, 2), 256, 0, stream>>>(T, nullptr, img + IMG_P2, b_p2, Hs, nullptr);

        gemm3<128, 0, 32, 32, false, true>
            <<<dim3(128, 1), 256, 0, stream>>>(Hs, nullptr, img + IMG_PI, b_pi, out, mask);
    }
}

// Round 10
// 225.761 us; speedup vs baseline: 2.8348x; 2.8348x over previous
//
#include <hip/hip_runtime.h>
#include <hip/hip_bf16.h>

// Graph Actor Model — R10: R6-proven 9-dispatch pipeline; encoder fused into
// the build dispatch via a ZERO-LDS direct-global-B GEMM (keeps build at full
// occupancy — R9 showed coop/LDS-sharing caps build at 520 GB/s).
// Dispatches: memset(cnt) -> buildpack_enc -> prop1 -> prop2 -> gcn -> gd
//             -> p1 -> p2 -> pi

#define NN   8192
#define EPAD 128
#define BUILD_GRID 2048
#define ENC_BLOCKS 128

typedef __attribute__((ext_vector_type(8))) short bf16x8;
typedef __attribute__((ext_vector_type(4))) float f32x4;

// weight image byte offsets (tile = BN*128 bytes) — head layers only
#define IMG_GCN 0u
#define IMG_GD  262144u
#define IMG_P1  524288u
#define IMG_P2  786432u
#define IMG_PI  851968u

// ---------- split-bf16 helpers (R4/R6 proven) ----------

__device__ __forceinline__ unsigned f32_to_split(float v) {
    unsigned b = __builtin_bit_cast(unsigned, v);
    unsigned hi = (b + 0x7fffu + ((b >> 16) & 1u)) & 0xffff0000u;
    float lo = v - __builtin_bit_cast(float, hi);
    unsigned lb = __builtin_bit_cast(unsigned, lo);
    unsigned lo16 = (lb + 0x7fffu + ((lb >> 16) & 1u)) >> 16;
    return hi | lo16;
}

__device__ __forceinline__ void unpack_frags(const uint4& q0, const uint4& q1,
                                             bf16x8& hi, bf16x8& lo) {
    union { unsigned u[4]; bf16x8 v; } H, L;
    H.u[0] = (q0.y & 0xffff0000u) | (q0.x >> 16);
    H.u[1] = (q0.w & 0xffff0000u) | (q0.z >> 16);
    H.u[2] = (q1.y & 0xffff0000u) | (q1.x >> 16);
    H.u[3] = (q1.w & 0xffff0000u) | (q1.z >> 16);
    L.u[0] = (q0.y << 16) | (q0.x & 0xffffu);
    L.u[1] = (q0.w << 16) | (q0.z & 0xffffu);
    L.u[2] = (q1.y << 16) | (q1.x & 0xffffu);
    L.u[3] = (q1.w << 16) | (q1.z & 0xffffu);
    hi = H.v; lo = L.v;
}

__device__ __forceinline__ void split2(float v, unsigned short& h, unsigned short& l) {
    unsigned b = __builtin_bit_cast(unsigned, v);
    unsigned hr = (b + 0x7fffu + ((b >> 16) & 1u)) & 0xffff0000u;
    h = (unsigned short)(hr >> 16);
    float lo = v - __builtin_bit_cast(float, hr);
    unsigned lb = __builtin_bit_cast(unsigned, lo);
    l = (unsigned short)((lb + 0x7fffu + ((lb >> 16) & 1u)) >> 16);
}

__device__ __forceinline__ void splitfrag(const float4& v0, const float4& v1,
                                          bf16x8& ah, bf16x8& al) {
    union { unsigned short us[8]; bf16x8 v; } H, L;
    float vv[8] = {v0.x, v0.y, v0.z, v0.w, v1.x, v1.y, v1.z, v1.w};
    #pragma unroll
    for (int j = 0; j < 8; ++j) {
        unsigned short h, l;
        split2(vv[j], h, l);
        H.us[j] = h; L.us[j] = l;
    }
    ah = H.v; al = L.v;
}

__device__ __forceinline__ void gload_lds16(const void* g, void* l) {
    typedef const __attribute__((address_space(1))) unsigned int GU;
    typedef __attribute__((address_space(3))) unsigned int LU;
    __builtin_amdgcn_global_load_lds((GU*)g, (LU*)l, 16, 0, 0);
}

// ---------- build (8-deep independent loads; R6 proven) ----------

__device__ __forceinline__ void handle_chunk(const uint4& v, size_t chunk,
                                             int* cnt, int* edges) {
    if ((v.x | v.y | v.z | v.w) != 0u) {
        size_t base = chunk * 4;
        int r  = (int)(base / NN);
        int c0 = (int)(base % NN);
        unsigned e[4] = {v.x, v.y, v.z, v.w};
        #pragma unroll
        for (int j = 0; j < 4; ++j) {
            if (e[j] != 0u) {
                int c = c0 + j;
                int slot = atomicAdd(&cnt[c], 1);
                if (slot < EPAD) edges[(size_t)c * EPAD + slot] = r;
            }
        }
    }
}

__device__ void build_part(const uint4* __restrict__ adj4,
                           int* __restrict__ cnt, int* __restrict__ edges,
                           size_t tid, size_t nthr) {
    const size_t total = (size_t)NN * NN / 4;
    const size_t nfull = total / (nthr * 8);
    for (size_t b = 0; b < nfull; ++b) {
        size_t i0 = tid + b * 8 * nthr;
        uint4 v0 = adj4[i0 + 0 * nthr];
        uint4 v1 = adj4[i0 + 1 * nthr];
        uint4 v2 = adj4[i0 + 2 * nthr];
        uint4 v3 = adj4[i0 + 3 * nthr];
        uint4 v4 = adj4[i0 + 4 * nthr];
        uint4 v5 = adj4[i0 + 5 * nthr];
        uint4 v6 = adj4[i0 + 6 * nthr];
        uint4 v7 = adj4[i0 + 7 * nthr];
        handle_chunk(v0, i0 + 0 * nthr, cnt, edges);
        handle_chunk(v1, i0 + 1 * nthr, cnt, edges);
        handle_chunk(v2, i0 + 2 * nthr, cnt, edges);
        handle_chunk(v3, i0 + 3 * nthr, cnt, edges);
        handle_chunk(v4, i0 + 4 * nthr, cnt, edges);
        handle_chunk(v5, i0 + 5 * nthr, cnt, edges);
        handle_chunk(v6, i0 + 6 * nthr, cnt, edges);
        handle_chunk(v7, i0 + 7 * nthr, cnt, edges);
    }
    for (size_t i = tid + nfull * 8 * nthr; i < total; i += nthr) {
        uint4 v = adj4[i];
        handle_chunk(v, i, cnt, edges);
    }
}

// ---------- weight image packing (head layers; R6 proven) ----------

__device__ void pack_layer(const float* W, int NOUT, int K, int BN_,
                           unsigned imgoff, int rank, int nblk,
                           unsigned char* img) {
    const int nks = K / 32;
    const int total = (NOUT / BN_) * nks * BN_ * 8;
    const int tileb = BN_ * 128;
    for (int u = rank * 256 + threadIdx.x; u < total; u += nblk * 256) {
        int tile = u / (BN_ * 8);
        int rem  = u - tile * (BN_ * 8);
        int n    = rem >> 3;
        int c    = rem & 7;
        int nh   = tile / nks;
        int ks   = tile - nh * nks;
        int col  = nh * BN_ + n;
        int kb   = ks * 32 + c * 4;
        uint4 q;
        q.x = f32_to_split(W[(size_t)(kb + 0) * NOUT + col]);
        q.y = f32_to_split(W[(size_t)(kb + 1) * NOUT + col]);
        q.z = f32_to_split(W[(size_t)(kb + 2) * NOUT + col]);
        q.w = f32_to_split(W[(size_t)(kb + 3) * NOUT + col]);
        *(uint4*)(img + imgoff + (size_t)tile * tileb + n * 128 + ((c ^ (n & 7)) << 4)) = q;
    }
}

__device__ void pack_dispatch(int pb,
    const float* Wgcn, const float* Wgd, const float* Wp1, const float* Wp2,
    const float* Wpi, unsigned char* img)
{
    if (pb < 2)      pack_layer(Wgcn, 256, 256, 64, IMG_GCN, pb,     2, img);
    else if (pb < 4) pack_layer(Wgd,  256, 256, 64, IMG_GD,  pb - 2, 2, img);
    else if (pb < 6) pack_layer(Wp1,  128, 512, 64, IMG_P1,  pb - 4, 2, img);
    else if (pb < 7) pack_layer(Wp2,  128, 128, 64, IMG_P2,  0,      1, img);
    else             pack_layer(Wpi,   32, 128, 32, IMG_PI,  0,      1, img);
}

// ---------- zero-LDS direct-global-B GEMM (encoder only) ----------
// 64 rows x 64 cols per call; B fragments read straight from W (f32, [K,NOUT])
// with in-register split. Lane layout identical to gemm_body: col index = lm,
// k = lk*8 + j  (doc-verified 16x16x32 A/B mapping).

template<int KK, int NOUT, bool RELU>
__device__ void gemm_direct(int row0, int col0,
    const float* __restrict__ A, const float* __restrict__ W,
    const float* __restrict__ bias, float* __restrict__ C)
{
    constexpr int NKS = KK / 32;
    const int t    = threadIdx.x;
    const int lane = t & 63;
    const int wave = t >> 6;
    const int wr   = wave >> 1;
    const int wc   = wave & 1;
    const int lm   = lane & 15;
    const int lk   = lane >> 4;

    f32x4 acc[2][2];
    #pragma unroll
    for (int i = 0; i < 2; ++i)
        #pragma unroll
        for (int j = 0; j < 2; ++j) {
            acc[i][j][0] = 0.f; acc[i][j][1] = 0.f;
            acc[i][j][2] = 0.f; acc[i][j][3] = 0.f;
        }

    #pragma unroll
    for (int ks = 0; ks < NKS; ++ks) {
        const int kg = ks * 32 + lk * 8;
        bf16x8 bh[2], bl[2];
        #pragma unroll
        for (int fn = 0; fn < 2; ++fn) {
            int n = col0 + wc * 32 + fn * 16 + lm;
            union { unsigned short us[8]; bf16x8 v; } H, L;
            #pragma unroll
            for (int j = 0; j < 8; ++j) {
                unsigned short hh, ll;
                split2(W[(size_t)(kg + j) * NOUT + n], hh, ll);
                H.us[j] = hh; L.us[j] = ll;
            }
            bh[fn] = H.v; bl[fn] = L.v;
        }
        #pragma unroll
        for (int fm = 0; fm < 2; ++fm) {
            int m = row0 + wr * 32 + fm * 16 + lm;
            float4 v0 = *(const float4*)(A + (size_t)m * KK + kg);
            float4 v1 = *(const float4*)(A + (size_t)m * KK + kg + 4);
            bf16x8 ah, al;
            splitfrag(v0, v1, ah, al);
            #pragma unroll
            for (int fn = 0; fn < 2; ++fn) {
                acc[fm][fn] = __builtin_amdgcn_mfma_f32_16x16x32_bf16(ah, bh[fn], acc[fm][fn], 0, 0, 0);
                acc[fm][fn] = __builtin_amdgcn_mfma_f32_16x16x32_bf16(ah, bl[fn], acc[fm][fn], 0, 0, 0);
                acc[fm][fn] = __builtin_amdgcn_mfma_f32_16x16x32_bf16(al, bh[fn], acc[fm][fn], 0, 0, 0);
            }
        }
    }

    #pragma unroll
    for (int fm = 0; fm < 2; ++fm) {
        #pragma unroll
        for (int fn = 0; fn < 2; ++fn) {
            int col = col0 + wc * 32 + fn * 16 + lm;
            float b = bias[col];
            #pragma unroll
            for (int q = 0; q < 4; ++q) {
                int row = row0 + wr * 32 + fm * 16 + lk * 4 + q;
                float v = acc[fm][fn][q] + b;
                if (RELU) v = fmaxf(v, 0.f);
                C[(size_t)row * NOUT + col] = v;
            }
        }
    }
}

// encoder block: e1 (64x64) then e2 (64x256), row-block-local via T1 global
__device__ void enc_block(int eb, const float* feat,
                          const float* We1, const float* be1,
                          const float* We2, const float* be2,
                          float* T1, float* X) {
    const int r0 = eb * 64;
    gemm_direct<64, 64, true>(r0, 0, feat, We1, be1, T1);
    __threadfence();
    __syncthreads();
    #pragma unroll
    for (int cb = 0; cb < 4; ++cb)
        gemm_direct<64, 256, true>(r0, cb * 64, T1, We2, be2, X);
}

// ---------- build + pack + encoder, one zero-LDS dispatch ----------

__global__ __launch_bounds__(256) void buildpack_enc_kernel(
    const uint4* adj4, int* cnt, int* edges, const float* feat,
    const float* We1, const float* be1, const float* We2, const float* be2,
    const float* Wgcn, const float* Wgd, const float* Wp1, const float* Wp2,
    const float* Wpi, float* T1, float* X, unsigned char* img)
{
    const int bid = blockIdx.x;
    if (bid < 8) {
        pack_dispatch(bid, Wgcn, Wgd, Wp1, Wp2, Wpi, img);
    } else if (bid < 8 + ENC_BLOCKS) {
        enc_block(bid - 8, feat, We1, be1, We2, be2, T1, X);
    }
    build_part(adj4, cnt, edges, (size_t)bid * 256 + threadIdx.x,
               (size_t)BUILD_GRID * 256);
}

// ---------- sparse propagation (R6 proven) ----------

__global__ __launch_bounds__(256) void prop_kernel(
    const float* __restrict__ h, const int* __restrict__ cnt,
    const int* __restrict__ edges, float* __restrict__ out)
{
    __shared__ int   se[2][128];
    __shared__ float sd[2][128];
    const int half = threadIdx.x >> 7;
    const int tl   = threadIdx.x & 127;
    const int c = blockIdx.x * 2 + half;
    int n = cnt[c]; if (n > EPAD) n = EPAD;
    if (tl < n) {
        int r = edges[(size_t)c * EPAD + tl];
        se[half][tl] = r;
        int dr = cnt[r];
        sd[half][tl] = dr > 0 ? rsqrtf((float)dr) : 0.f;
    }
    __syncthreads();
    float2 a[8];
    #pragma unroll
    for (int j = 0; j < 8; ++j) { a[j].x = 0.f; a[j].y = 0.f; }
    int i = 0;
    for (; i + 8 <= n; i += 8) {
        #pragma unroll
        for (int j = 0; j < 8; ++j) {
            float2 v = *(const float2*)&h[(size_t)se[half][i + j] * 256 + tl * 2];
            float s = sd[half][i + j];
            a[j].x += s * v.x; a[j].y += s * v.y;
        }
    }
    for (; i < n; ++i) {
        float2 v = *(const float2*)&h[(size_t)se[half][i] * 256 + tl * 2];
        float s = sd[half][i];
        a[0].x += s * v.x; a[0].y += s * v.y;
    }
    int dc = cnt[c];
    float di = dc > 0 ? rsqrtf((float)dc) : 0.f;
    float2 r2;
    r2.x = di * (((a[0].x + a[1].x) + (a[2].x + a[3].x)) + ((a[4].x + a[5].x) + (a[6].x + a[7].x)));
    r2.y = di * (((a[0].y + a[1].y) + (a[2].y + a[3].y)) + ((a[4].y + a[5].y) + (a[6].y + a[7].y)));
    *(float2*)&out[(size_t)c * 256 + tl * 2] = r2;
}

// ---------- barrier-free-K MFMA GEMM (R6 proven) ----------

template<int K1, int K2, int NOUT, int BN, bool RELU, bool MASK>
__device__ void gemm_body(int row0, int col0,
    const float* __restrict__ A1, const float* __restrict__ A2,
    const unsigned char* __restrict__ imgp, const float* __restrict__ bias,
    float* __restrict__ C, const float* __restrict__ maskv,
    unsigned char* Bs)
{
    constexpr int K      = K1 + K2;
    constexpr int NKS    = K / 32;
    constexpr int TILEB  = BN * 128;
    constexpr int WTILES = NKS > 4 ? 4 : NKS;   // <=32 KB window
    constexpr int NWIN   = NKS / WTILES;
    constexpr int WN     = BN / 2;
    constexpr int FN     = WN / 16;
    constexpr int NCHUNK = WTILES * TILEB / 1024;

    const int t    = threadIdx.x;
    const int lane = t & 63;
    const int wave = t >> 6;
    const int wr   = wave >> 1;
    const int wc   = wave & 1;
    const int lm   = lane & 15;
    const int lk   = lane >> 4;

    f32x4 acc[2][FN];
    #pragma unroll
    for (int i = 0; i < 2; ++i)
        #pragma unroll
        for (int j = 0; j < FN; ++j) {
            acc[i][j][0] = 0.f; acc[i][j][1] = 0.f;
            acc[i][j][2] = 0.f; acc[i][j][3] = 0.f;
        }

    #pragma unroll
    for (int w = 0; w < NWIN; ++w) {
        if (w > 0) __syncthreads();
        #pragma unroll
        for (int i = wave; i < NCHUNK; i += 4)
            gload_lds16(imgp + (size_t)w * WTILES * TILEB + (size_t)i * 1024 + lane * 16,
                        Bs + (size_t)i * 1024);
        __syncthreads();

        #pragma unroll
        for (int kl = 0; kl < WTILES; ++kl) {
            const int ks = w * WTILES + kl;
            const int kg = ks * 32 + lk * 8;
            bf16x8 bh[FN], bl[FN];
            #pragma unroll
            for (int fn = 0; fn < FN; ++fn) {
                int n = wc * WN + fn * 16 + lm;
                const unsigned char* bb = Bs + kl * TILEB + n * 128;
                uint4 q0 = *(const uint4*)(bb + (((lk * 2 + 0) ^ (n & 7)) << 4));
                uint4 q1 = *(const uint4*)(bb + (((lk * 2 + 1) ^ (n & 7)) << 4));
                unpack_frags(q0, q1, bh[fn], bl[fn]);
            }
            #pragma unroll
            for (int fm = 0; fm < 2; ++fm) {
                int m = row0 + wr * 32 + fm * 16 + lm;
                const float* ap; int kk = kg;
                if constexpr (K2 > 0) {
                    if (kg < K1) { ap = A1 + (size_t)m * K1; }
                    else         { ap = A2 + (size_t)m * K2; kk = kg - K1; }
                } else {
                    ap = A1 + (size_t)m * K1;
                }
                float4 v0 = *(const float4*)(ap + kk);
                float4 v1 = *(const float4*)(ap + kk + 4);
                bf16x8 ah, al;
                splitfrag(v0, v1, ah, al);
                #pragma unroll
                for (int fn = 0; fn < FN; ++fn) {
                    acc[fm][fn] = __builtin_amdgcn_mfma_f32_16x16x32_bf16(ah, bh[fn], acc[fm][fn], 0, 0, 0);
                    acc[fm][fn] = __builtin_amdgcn_mfma_f32_16x16x32_bf16(ah, bl[fn], acc[fm][fn], 0, 0, 0);
                    acc[fm][fn] = __builtin_amdgcn_mfma_f32_16x16x32_bf16(al, bh[fn], acc[fm][fn], 0, 0, 0);
                }
            }
        }
    }

    #pragma unroll
    for (int fm = 0; fm < 2; ++fm) {
        #pragma unroll
        for (int fn = 0; fn < FN; ++fn) {
            int col = col0 + wc * WN + fn * 16 + lm;
            float b = bias[col];
            #pragma unroll
            for (int q = 0; q < 4; ++q) {
                int row = row0 + wr * 32 + fm * 16 + lk * 4 + q;
                float v = acc[fm][fn][q] + b;
                if (RELU) v = fmaxf(v, 0.f);
                if (MASK) v *= maskv[row];
                C[(size_t)row * NOUT + col] = v;
            }
        }
    }
}

template<int K1, int K2, int NOUT, int BN, bool RELU, bool MASK>
__global__ __launch_bounds__(256) void gemm3(
    const float* __restrict__ A1, const float* __restrict__ A2,
    const unsigned char* __restrict__ img, const float* __restrict__ bias,
    float* __restrict__ C, const float* __restrict__ maskv)
{
    constexpr int NKS   = (K1 + K2) / 32;
    constexpr int TILEB = BN * 128;
    constexpr int WT    = NKS > 4 ? 4 : NKS;
    __shared__ unsigned char Bs[WT * TILEB];
    gemm_body<K1, K2, NOUT, BN, RELU, MASK>(
        blockIdx.x * 64, blockIdx.y * BN, A1, A2,
        img + (size_t)blockIdx.y * NKS * TILEB, bias, C, maskv, Bs);
}

// ---------- launch ----------

extern "C" void kernel_launch(void* const* d_in, const int* in_sizes, int n_in,
                              void* d_out, int out_size, void* d_ws, size_t ws_size,
                              hipStream_t stream) {
    const float* features = (const float*)d_in[0];
    const uint4* adj4     = (const uint4*)d_in[1];
    const float* mask     = (const float*)d_in[2];
    const float* W_e1  = (const float*)d_in[3];
    const float* b_e1  = (const float*)d_in[4];
    const float* W_e2  = (const float*)d_in[5];
    const float* b_e2  = (const float*)d_in[6];
    const float* W_gcn = (const float*)d_in[7];
    const float* b_gcn = (const float*)d_in[8];
    const float* W_gd  = (const float*)d_in[9];
    const float* b_gd  = (const float*)d_in[10];
    const float* W_p1  = (const float*)d_in[11];
    const float* b_p1  = (const float*)d_in[12];
    const float* W_p2  = (const float*)d_in[13];
    const float* b_p2  = (const float*)d_in[14];
    const float* W_pi  = (const float*)d_in[15];
    const float* b_pi  = (const float*)d_in[16];
    float* out = (float*)d_out;

    float* ws = (float*)d_ws;
    float* X   = ws;                                  // [NN,256]
    float* T   = X  + (size_t)NN * 256;               // [NN,256] (P1 [NN,128])
    float* Hs  = T  + (size_t)NN * 256;               // [NN,256] (P2 [NN,128])
    float* T1  = Hs + (size_t)NN * 256;               // [NN,64] enc intermediate
    int* cnt   = (int*)(T1 + (size_t)NN * 64);        // [NN]
    int* edges = cnt + NN;                            // [NN][EPAD]
    unsigned char* img = (unsigned char*)(edges + (size_t)NN * EPAD);

    hipMemsetAsync(cnt, 0, NN * sizeof(int), stream);

    // build || pack || encoder (zero-LDS dispatch, full build occupancy)
    buildpack_enc_kernel<<<BUILD_GRID, 256, 0, stream>>>(
        adj4, cnt, edges, features,
        W_e1, b_e1, W_e2, b_e2,
        W_gcn, W_gd, W_p1, W_p2, W_pi, T1, X, img);

    // SGConv K=2
    prop_kernel<<<NN / 2, 256, 0, stream>>>(X, cnt, edges, T);
    prop_kernel<<<NN / 2, 256, 0, stream>>>(T, cnt, edges, Hs);

    // Xg = relu(Hs@Wgcn+b) -> T ; Xg2 = relu(T@Wgd+b) -> Hs
    gemm3<256, 0, 256, 64, true, false>
        <<<dim3(128, 4), 256, 0, stream>>>(Hs, nullptr, img + IMG_GCN, b_gcn, T, nullptr);
    gemm3<256, 0, 256, 64, true, false>
        <<<dim3(128, 4), 256, 0, stream>>>(T, nullptr, img + IMG_GD, b_gd, Hs, nullptr);

    // P1 = relu([Xg2|X]@Wp1+b) -> T ; P2 = relu(P1@Wp2+b) -> Hs
    gemm3<256, 256, 128, 64, true, false>
        <<<dim3(128, 2), 256, 0, stream>>>(Hs, X, img + IMG_P1, b_p1, T, nullptr);
    gemm3<128, 0, 128, 64, true, false>
        <<<dim3(128, 2), 256, 0, stream>>>(T, nullptr, img + IMG_P2, b_p2, Hs, nullptr);

    // pi = (P2@Wpi+b)*mask -> out
    gemm3<128, 0, 32, 32, false, true>
        <<<dim3(128, 1), 256, 0, stream>>>(Hs, nullptr, img + IMG_PI, b_pi, out, mask);
}

// Round 11
// 184.786 us; speedup vs baseline: 3.4635x; 1.2217x over previous
//
#include <hip/hip_runtime.h>
#include <hip/hip_bf16.h>

// Graph Actor Model — R11 = R6 structure (proven 194us) + two targeted fixes:
//  - build: block-contiguous 128KB segments (was device-wide stride -> DRAM
//    row thrash); 8 independent loads in flight
//  - prop: one wave per column, float4 lanes, 8-deep gather pipeline
// Dispatches: memset -> buildpack -> e1 -> e2 -> prop -> prop -> gcn -> gd
//             -> p1 -> p2 -> pi

#define NN   8192
#define EPAD 128
#define BUILD_BLOCKS 2048
#define PACK_BLOCKS  8

typedef __attribute__((ext_vector_type(8))) short bf16x8;
typedef __attribute__((ext_vector_type(4))) float f32x4;

// weight image byte offsets (tile = BN*128 bytes)
#define IMG_E1  0u
#define IMG_E2  16384u
#define IMG_GCN 81920u
#define IMG_GD  344064u
#define IMG_P1  606208u
#define IMG_P2  868352u
#define IMG_PI  933888u

// ---------- split-bf16 helpers (R4/R6 proven) ----------

__device__ __forceinline__ unsigned f32_to_split(float v) {
    unsigned b = __builtin_bit_cast(unsigned, v);
    unsigned hi = (b + 0x7fffu + ((b >> 16) & 1u)) & 0xffff0000u;
    float lo = v - __builtin_bit_cast(float, hi);
    unsigned lb = __builtin_bit_cast(unsigned, lo);
    unsigned lo16 = (lb + 0x7fffu + ((lb >> 16) & 1u)) >> 16;
    return hi | lo16;
}

__device__ __forceinline__ void unpack_frags(const uint4& q0, const uint4& q1,
                                             bf16x8& hi, bf16x8& lo) {
    union { unsigned u[4]; bf16x8 v; } H, L;
    H.u[0] = (q0.y & 0xffff0000u) | (q0.x >> 16);
    H.u[1] = (q0.w & 0xffff0000u) | (q0.z >> 16);
    H.u[2] = (q1.y & 0xffff0000u) | (q1.x >> 16);
    H.u[3] = (q1.w & 0xffff0000u) | (q1.z >> 16);
    L.u[0] = (q0.y << 16) | (q0.x & 0xffffu);
    L.u[1] = (q0.w << 16) | (q0.z & 0xffffu);
    L.u[2] = (q1.y << 16) | (q1.x & 0xffffu);
    L.u[3] = (q1.w << 16) | (q1.z & 0xffffu);
    hi = H.v; lo = L.v;
}

__device__ __forceinline__ void split2(float v, unsigned short& h, unsigned short& l) {
    unsigned b = __builtin_bit_cast(unsigned, v);
    unsigned hr = (b + 0x7fffu + ((b >> 16) & 1u)) & 0xffff0000u;
    h = (unsigned short)(hr >> 16);
    float lo = v - __builtin_bit_cast(float, hr);
    unsigned lb = __builtin_bit_cast(unsigned, lo);
    l = (unsigned short)((lb + 0x7fffu + ((lb >> 16) & 1u)) >> 16);
}

__device__ __forceinline__ void splitfrag(const float4& v0, const float4& v1,
                                          bf16x8& ah, bf16x8& al) {
    union { unsigned short us[8]; bf16x8 v; } H, L;
    float vv[8] = {v0.x, v0.y, v0.z, v0.w, v1.x, v1.y, v1.z, v1.w};
    #pragma unroll
    for (int j = 0; j < 8; ++j) {
        unsigned short h, l;
        split2(vv[j], h, l);
        H.us[j] = h; L.us[j] = l;
    }
    ah = H.v; al = L.v;
}

__device__ __forceinline__ void gload_lds16(const void* g, void* l) {
    typedef const __attribute__((address_space(1))) unsigned int GU;
    typedef __attribute__((address_space(3))) unsigned int LU;
    __builtin_amdgcn_global_load_lds((GU*)g, (LU*)l, 16, 0, 0);
}

// ---------- build: block-contiguous segments, 8-deep ----------

__device__ __forceinline__ void handle_chunk(const uint4& v, size_t chunk,
                                             int* cnt, int* edges) {
    if ((v.x | v.y | v.z | v.w) != 0u) {
        size_t base = chunk * 4;
        int r  = (int)(base / NN);
        int c0 = (int)(base % NN);
        unsigned e[4] = {v.x, v.y, v.z, v.w};
        #pragma unroll
        for (int j = 0; j < 4; ++j) {
            if (e[j] != 0u) {
                int c = c0 + j;
                int slot = atomicAdd(&cnt[c], 1);
                if (slot < EPAD) edges[(size_t)c * EPAD + slot] = r;
            }
        }
    }
}

__device__ void build_part_seg(const uint4* __restrict__ adj4,
                               int* __restrict__ cnt, int* __restrict__ edges,
                               int bid) {
    // block b owns chunks [b*8192, (b+1)*8192): a contiguous 128 KB region.
    // 256 threads x 32 chunks = 4 batches of 8 independent loads.
    const size_t seg = (size_t)bid * 8192;
    const size_t t0  = seg + threadIdx.x;
    #pragma unroll
    for (int b = 0; b < 4; ++b) {
        size_t i0 = t0 + (size_t)(b * 8) * 256;
        uint4 v0 = adj4[i0 + 0 * 256];
        uint4 v1 = adj4[i0 + 1 * 256];
        uint4 v2 = adj4[i0 + 2 * 256];
        uint4 v3 = adj4[i0 + 3 * 256];
        uint4 v4 = adj4[i0 + 4 * 256];
        uint4 v5 = adj4[i0 + 5 * 256];
        uint4 v6 = adj4[i0 + 6 * 256];
        uint4 v7 = adj4[i0 + 7 * 256];
        handle_chunk(v0, i0 + 0 * 256, cnt, edges);
        handle_chunk(v1, i0 + 1 * 256, cnt, edges);
        handle_chunk(v2, i0 + 2 * 256, cnt, edges);
        handle_chunk(v3, i0 + 3 * 256, cnt, edges);
        handle_chunk(v4, i0 + 4 * 256, cnt, edges);
        handle_chunk(v5, i0 + 5 * 256, cnt, edges);
        handle_chunk(v6, i0 + 6 * 256, cnt, edges);
        handle_chunk(v7, i0 + 7 * 256, cnt, edges);
    }
}

// ---------- weight image packing (R6 proven) ----------

__device__ void pack_layer(const float* W, int NOUT, int K, int BN_,
                           unsigned imgoff, int rank, int nblk,
                           unsigned char* img) {
    const int nks = K / 32;
    const int total = (NOUT / BN_) * nks * BN_ * 8;
    const int tileb = BN_ * 128;
    for (int u = rank * 256 + threadIdx.x; u < total; u += nblk * 256) {
        int tile = u / (BN_ * 8);
        int rem  = u - tile * (BN_ * 8);
        int n    = rem >> 3;
        int c    = rem & 7;
        int nh   = tile / nks;
        int ks   = tile - nh * nks;
        int col  = nh * BN_ + n;
        int kb   = ks * 32 + c * 4;
        uint4 q;
        q.x = f32_to_split(W[(size_t)(kb + 0) * NOUT + col]);
        q.y = f32_to_split(W[(size_t)(kb + 1) * NOUT + col]);
        q.z = f32_to_split(W[(size_t)(kb + 2) * NOUT + col]);
        q.w = f32_to_split(W[(size_t)(kb + 3) * NOUT + col]);
        *(uint4*)(img + imgoff + (size_t)tile * tileb + n * 128 + ((c ^ (n & 7)) << 4)) = q;
    }
}

__global__ __launch_bounds__(256) void buildpack_kernel(
    const uint4* adj4, int* cnt, int* edges,
    const float* We1, const float* We2, const float* Wgcn, const float* Wgd,
    const float* Wp1, const float* Wp2, const float* Wpi, unsigned char* img)
{
    int bid = blockIdx.x;
    if (bid < BUILD_BLOCKS) {
        build_part_seg(adj4, cnt, edges, bid);
    } else {
        int pb = bid - BUILD_BLOCKS;
        if (pb < 2)      pack_layer(Wgcn, 256, 256, 64, IMG_GCN, pb,     2, img);
        else if (pb < 4) pack_layer(Wgd,  256, 256, 64, IMG_GD,  pb - 2, 2, img);
        else if (pb < 6) pack_layer(Wp1,  128, 512, 64, IMG_P1,  pb - 4, 2, img);
        else if (pb < 7) { pack_layer(We2, 256,  64, 64, IMG_E2, 0, 1, img);
                           pack_layer(Wp2, 128, 128, 64, IMG_P2, 0, 1, img); }
        else             { pack_layer(We1,  64,  64, 64, IMG_E1, 0, 1, img);
                           pack_layer(Wpi,  32, 128, 32, IMG_PI, 0, 1, img); }
    }
}

// ---------- sparse propagation: 1 wave per column, float4 lanes, 8-deep ----------

__global__ __launch_bounds__(256) void prop_kernel(
    const float* __restrict__ h, const int* __restrict__ cnt,
    const int* __restrict__ edges, float* __restrict__ out)
{
    __shared__ int   se[4][EPAD];
    __shared__ float sd[4][EPAD];
    const int wave = threadIdx.x >> 6;
    const int lane = threadIdx.x & 63;
    const int c = blockIdx.x * 4 + wave;
    int n = cnt[c]; if (n > EPAD) n = EPAD;
    for (int i = lane; i < n; i += 64) {
        int r = edges[(size_t)c * EPAD + i];
        se[wave][i] = r;
        int dr = cnt[r];
        sd[wave][i] = dr > 0 ? rsqrtf((float)dr) : 0.f;
    }
    __syncthreads();
    float4 a[8];
    #pragma unroll
    for (int j = 0; j < 8; ++j) { a[j].x = 0.f; a[j].y = 0.f; a[j].z = 0.f; a[j].w = 0.f; }
    int i = 0;
    for (; i + 8 <= n; i += 8) {
        #pragma unroll
        for (int j = 0; j < 8; ++j) {
            float4 v = *(const float4*)&h[(size_t)se[wave][i + j] * 256 + lane * 4];
            float s = sd[wave][i + j];
            a[j].x += s * v.x; a[j].y += s * v.y; a[j].z += s * v.z; a[j].w += s * v.w;
        }
    }
    for (; i < n; ++i) {
        float4 v = *(const float4*)&h[(size_t)se[wave][i] * 256 + lane * 4];
        float s = sd[wave][i];
        a[0].x += s * v.x; a[0].y += s * v.y; a[0].z += s * v.z; a[0].w += s * v.w;
    }
    int dc = cnt[c];
    float di = dc > 0 ? rsqrtf((float)dc) : 0.f;
    float4 r4;
    r4.x = di * (((a[0].x + a[1].x) + (a[2].x + a[3].x)) + ((a[4].x + a[5].x) + (a[6].x + a[7].x)));
    r4.y = di * (((a[0].y + a[1].y) + (a[2].y + a[3].y)) + ((a[4].y + a[5].y) + (a[6].y + a[7].y)));
    r4.z = di * (((a[0].z + a[1].z) + (a[2].z + a[3].z)) + ((a[4].z + a[5].z) + (a[6].z + a[7].z)));
    r4.w = di * (((a[0].w + a[1].w) + (a[2].w + a[3].w)) + ((a[4].w + a[5].w) + (a[6].w + a[7].w)));
    *(float4*)&out[(size_t)c * 256 + lane * 4] = r4;
}

// ---------- barrier-free-K MFMA GEMM (R6 proven, verbatim) ----------

template<int K1, int K2, int NOUT, int BN, bool RELU, bool MASK>
__global__ __launch_bounds__(256) void gemm3(
    const float* __restrict__ A1, const float* __restrict__ A2,
    const unsigned char* __restrict__ img, const float* __restrict__ bias,
    float* __restrict__ C, const float* __restrict__ maskv)
{
    constexpr int K      = K1 + K2;
    constexpr int NKS    = K / 32;
    constexpr int TILEB  = BN * 128;
    constexpr int WTILES = NKS > 4 ? 4 : NKS;   // 32 KB max LDS window
    constexpr int NWIN   = NKS / WTILES;
    constexpr int WN     = BN / 2;
    constexpr int FN     = WN / 16;
    constexpr int NCHUNK = WTILES * TILEB / 1024;

    __shared__ unsigned char Bs[WTILES * TILEB];

    const int t    = threadIdx.x;
    const int lane = t & 63;
    const int wave = t >> 6;
    const int wr   = wave >> 1;
    const int wc   = wave & 1;
    const int lm   = lane & 15;
    const int lk   = lane >> 4;
    const int row0 = blockIdx.x * 64;
    const int col0 = blockIdx.y * BN;
    const unsigned char* imgp = img + (size_t)blockIdx.y * NKS * TILEB;

    f32x4 acc[2][FN];
    #pragma unroll
    for (int i = 0; i < 2; ++i)
        #pragma unroll
        for (int j = 0; j < FN; ++j) {
            acc[i][j][0] = 0.f; acc[i][j][1] = 0.f;
            acc[i][j][2] = 0.f; acc[i][j][3] = 0.f;
        }

    #pragma unroll
    for (int w = 0; w < NWIN; ++w) {
        if (w > 0) __syncthreads();
        #pragma unroll
        for (int i = wave; i < NCHUNK; i += 4)
            gload_lds16(imgp + (size_t)w * WTILES * TILEB + (size_t)i * 1024 + lane * 16,
                        Bs + (size_t)i * 1024);
        __syncthreads();

        #pragma unroll
        for (int kl = 0; kl < WTILES; ++kl) {
            const int ks = w * WTILES + kl;
            const int kg = ks * 32 + lk * 8;
            bf16x8 bh[FN], bl[FN];
            #pragma unroll
            for (int fn = 0; fn < FN; ++fn) {
                int n = wc * WN + fn * 16 + lm;
                const unsigned char* bb = Bs + kl * TILEB + n * 128;
                uint4 q0 = *(const uint4*)(bb + (((lk * 2 + 0) ^ (n & 7)) << 4));
                uint4 q1 = *(const uint4*)(bb + (((lk * 2 + 1) ^ (n & 7)) << 4));
                unpack_frags(q0, q1, bh[fn], bl[fn]);
            }
            #pragma unroll
            for (int fm = 0; fm < 2; ++fm) {
                int m = row0 + wr * 32 + fm * 16 + lm;
                const float* ap; int kk = kg;
                if constexpr (K2 > 0) {
                    if (kg < K1) { ap = A1 + (size_t)m * K1; }
                    else         { ap = A2 + (size_t)m * K2; kk = kg - K1; }
                } else {
                    ap = A1 + (size_t)m * K1;
                }
                float4 v0 = *(const float4*)(ap + kk);
                float4 v1 = *(const float4*)(ap + kk + 4);
                bf16x8 ah, al;
                splitfrag(v0, v1, ah, al);
                #pragma unroll
                for (int fn = 0; fn < FN; ++fn) {
                    acc[fm][fn] = __builtin_amdgcn_mfma_f32_16x16x32_bf16(ah, bh[fn], acc[fm][fn], 0, 0, 0);
                    acc[fm][fn] = __builtin_amdgcn_mfma_f32_16x16x32_bf16(ah, bl[fn], acc[fm][fn], 0, 0, 0);
                    acc[fm][fn] = __builtin_amdgcn_mfma_f32_16x16x32_bf16(al, bh[fn], acc[fm][fn], 0, 0, 0);
                }
            }
        }
    }

    #pragma unroll
    for (int fm = 0; fm < 2; ++fm) {
        #pragma unroll
        for (int fn = 0; fn < FN; ++fn) {
            int col = col0 + wc * WN + fn * 16 + lm;
            float b = bias[col];
            #pragma unroll
            for (int q = 0; q < 4; ++q) {
                int row = row0 + wr * 32 + fm * 16 + lk * 4 + q;
                float v = acc[fm][fn][q] + b;
                if (RELU) v = fmaxf(v, 0.f);
                if (MASK) v *= maskv[row];
                C[(size_t)row * NOUT + col] = v;
            }
        }
    }
}

// ---------- launch ----------

extern "C" void kernel_launch(void* const* d_in, const int* in_sizes, int n_in,
                              void* d_out, int out_size, void* d_ws, size_t ws_size,
                              hipStream_t stream) {
    const float* features = (const float*)d_in[0];
    const uint4* adj4     = (const uint4*)d_in[1];
    const float* mask     = (const float*)d_in[2];
    const float* W_e1  = (const float*)d_in[3];
    const float* b_e1  = (const float*)d_in[4];
    const float* W_e2  = (const float*)d_in[5];
    const float* b_e2  = (const float*)d_in[6];
    const float* W_gcn = (const float*)d_in[7];
    const float* b_gcn = (const float*)d_in[8];
    const float* W_gd  = (const float*)d_in[9];
    const float* b_gd  = (const float*)d_in[10];
    const float* W_p1  = (const float*)d_in[11];
    const float* b_p1  = (const float*)d_in[12];
    const float* W_p2  = (const float*)d_in[13];
    const float* b_p2  = (const float*)d_in[14];
    const float* W_pi  = (const float*)d_in[15];
    const float* b_pi  = (const float*)d_in[16];
    float* out = (float*)d_out;

    float* ws = (float*)d_ws;
    float* X   = ws;                                  // [NN,256]
    float* T   = X  + (size_t)NN * 256;               // [NN,256] (e1 out, P1)
    float* Hs  = T  + (size_t)NN * 256;               // [NN,256] (P2)
    int* cnt   = (int*)(Hs + (size_t)NN * 256);       // [NN]
    int* edges = cnt + NN;                            // [NN][EPAD]
    unsigned char* img = (unsigned char*)(edges + (size_t)NN * EPAD);

    hipMemsetAsync(cnt, 0, NN * sizeof(int), stream);

    // edge list (block-contiguous stream) || weight-image packing
    buildpack_kernel<<<BUILD_BLOCKS + PACK_BLOCKS, 256, 0, stream>>>(
        adj4, cnt, edges,
        W_e1, W_e2, W_gcn, W_gd, W_p1, W_p2, W_pi, img);

    // encoder: T = relu(F@We1+b), X = relu(T@We2+b)
    gemm3<64, 0, 64, 64, true, false>
        <<<dim3(128, 1), 256, 0, stream>>>(features, nullptr, img + IMG_E1, b_e1, T, nullptr);
    gemm3<64, 0, 256, 64, true, false>
        <<<dim3(128, 4), 256, 0, stream>>>(T, nullptr, img + IMG_E2, b_e2, X, nullptr);

    // SGConv K=2
    prop_kernel<<<NN / 4, 256, 0, stream>>>(X, cnt, edges, T);
    prop_kernel<<<NN / 4, 256, 0, stream>>>(T, cnt, edges, Hs);

    // Xg = relu(Hs@Wgcn+b) -> T ; Xg2 = relu(T@Wgd+b) -> Hs
    gemm3<256, 0, 256, 64, true, false>
        <<<dim3(128, 4), 256, 0, stream>>>(Hs, nullptr, img + IMG_GCN, b_gcn, T, nullptr);
    gemm3<256, 0, 256, 64, true, false>
        <<<dim3(128, 4), 256, 0, stream>>>(T, nullptr, img + IMG_GD, b_gd, Hs, nullptr);

    // P1 = relu([Xg2|X]@Wp1+b) -> T ; P2 = relu(P1@Wp2+b) -> Hs
    gemm3<256, 256, 128, 64, true, false>
        <<<dim3(128, 2), 256, 0, stream>>>(Hs, X, img + IMG_P1, b_p1, T, nullptr);
    gemm3<128, 0, 128, 64, true, false>
        <<<dim3(128, 2), 256, 0, stream>>>(T, nullptr, img + IMG_P2, b_p2, Hs, nullptr);

    // pi = (P2@Wpi+b)*mask -> out
    gemm3<128, 0, 32, 32, false, true>
        <<<dim3(128, 1), 256, 0, stream>>>(Hs, nullptr, img + IMG_PI, b_pi, out, mask);
}